// Round 12
// baseline (226.538 us; speedup 1.0000x reference)
//
#include <hip/hip_runtime.h>

#define N_USERS  100000
#define EMBED    128

typedef __attribute__((ext_vector_type(8))) short bf16x8;
typedef __attribute__((ext_vector_type(4))) float f32x4;

// ---------------------------------------------------------------- row pointers
__global__ __launch_bounds__(256) void rowptr_kernel(const int* __restrict__ rows,
                                                     int* __restrict__ row_ptr,
                                                     int n_rows, int n_edges) {
  int r = blockIdx.x * blockDim.x + threadIdx.x;
  if (r > n_rows) return;
  int lo = 0, hi = n_edges;
  while (lo < hi) {
    int mid = (lo + hi) >> 1;
    if (rows[mid] < r) lo = mid + 1; else hi = mid;
  }
  row_ptr[r] = lo;
}

// ---------------------------------------------------------------- W -> Wt bf16
__global__ __launch_bounds__(256) void wconv_kernel(const float* __restrict__ W0,
                                                    const float* __restrict__ W1,
                                                    uint* __restrict__ Wt0,
                                                    uint* __restrict__ Wt1) {
  const float* W  = blockIdx.x ? W1 : W0;
  uint*        Wt = blockIdx.x ? Wt1 : Wt0;
  for (int idx = threadIdx.x; idx < 128 * 64; idx += 256) {
    int n = idx >> 6;
    int kp = idx & 63;
    float a = W[(2 * kp) * 128 + n];
    float b = W[(2 * kp + 1) * 128 + n];
    uint o;
    asm("v_cvt_pk_bf16_f32 %0, %1, %2" : "=v"(o) : "v"(a), "v"(b));
    Wt[n * 64 + kp] = o;
  }
}

// ---------------------------------------------------------------- MFMA GEMM
// Y8(int8)[m][n] = quant(X @ W), per-row scale. Streams X -> Xcopy (layer 0).
__global__ __launch_bounds__(256) void gemm_kernel(const float* __restrict__ X,
                                                   const ushort* __restrict__ Wt,
                                                   unsigned char* __restrict__ Y8,
                                                   float* __restrict__ scale_arr,
                                                   float* __restrict__ Xcopy) {
  const int tid  = threadIdx.x;
  const int wave = tid >> 6;
  const int lane = tid & 63;
  const int l15  = lane & 15;
  const int lg   = lane >> 4;
  const int m    = blockIdx.x * 64 + wave * 16 + l15;
  const int mc   = m < N_USERS ? m : N_USERS - 1;
  const bool act = m < N_USERS;
  const float* xrow = X + (size_t)mc * EMBED;

  f32x4 acc[8];
  #pragma unroll
  for (int t = 0; t < 8; ++t) acc[t] = (f32x4){0.f, 0.f, 0.f, 0.f};

  #pragma unroll
  for (int s = 0; s < 4; ++s) {
    const int k0 = s * 32 + lg * 8;
    float4 xa = *(const float4*)(xrow + k0);
    float4 xb = *(const float4*)(xrow + k0 + 4);
    if (Xcopy && act) {
      *(float4*)(Xcopy + (size_t)m * EMBED + k0)     = xa;
      *(float4*)(Xcopy + (size_t)m * EMBED + k0 + 4) = xb;
    }
    union { bf16x8 v; uint u[4]; } bfr;
    asm("v_cvt_pk_bf16_f32 %0, %1, %2" : "=v"(bfr.u[0]) : "v"(xa.x), "v"(xa.y));
    asm("v_cvt_pk_bf16_f32 %0, %1, %2" : "=v"(bfr.u[1]) : "v"(xa.z), "v"(xa.w));
    asm("v_cvt_pk_bf16_f32 %0, %1, %2" : "=v"(bfr.u[2]) : "v"(xb.x), "v"(xb.y));
    asm("v_cvt_pk_bf16_f32 %0, %1, %2" : "=v"(bfr.u[3]) : "v"(xb.z), "v"(xb.w));
    #pragma unroll
    for (int nt = 0; nt < 8; ++nt) {
      union { bf16x8 v; uint4 u; } afr;
      afr.u = *(const uint4*)(Wt + (size_t)(nt * 16 + l15) * 128 + k0);
      acc[nt] = __builtin_amdgcn_mfma_f32_16x16x32_bf16(afr.v, bfr.v, acc[nt], 0, 0, 0);
    }
  }

  if (act) {
    float amax = 0.f;
    #pragma unroll
    for (int nt = 0; nt < 8; ++nt)
      #pragma unroll
      for (int i = 0; i < 4; ++i) amax = fmaxf(amax, fabsf(acc[nt][i]));
    amax = fmaxf(amax, __shfl_xor(amax, 16));
    amax = fmaxf(amax, __shfl_xor(amax, 32));
    const float inv = amax > 0.f ? 127.0f / amax : 0.f;
    if (lg == 0) scale_arr[m] = amax * (1.0f / 127.0f);

    unsigned char* yrow = Y8 + (size_t)m * EMBED;
    #pragma unroll
    for (int nt = 0; nt < 8; ++nt) {
      uint q = 0;
      #pragma unroll
      for (int i = 0; i < 4; ++i) {
        int qi = __float2int_rn(acc[nt][i] * inv) + 128;   // 1..255
        q |= (uint)qi << (8 * i);
      }
      *(uint*)(yrow + nt * 16 + lg * 4) = q;
    }
  }
}

// ---------------------------------------------------------------- dequant FMA (8 int8 via uint2)
__device__ __forceinline__ void fma8b(float* a, uint2 g, float vs) {
  float f;
  #define CVT_ACC(word, b, slot)                                        \
    asm("v_cvt_f32_ubyte" #b " %0, %1" : "=v"(f) : "v"(word));          \
    a[slot] = fmaf(vs, f, a[slot]);
  CVT_ACC(g.x, 0, 0) CVT_ACC(g.x, 1, 1) CVT_ACC(g.x, 2, 2) CVT_ACC(g.x, 3, 3)
  CVT_ACC(g.y, 0, 4) CVT_ACC(g.y, 1, 5) CVT_ACC(g.y, 2, 6) CVT_ACC(g.y, 3, 7)
  #undef CVT_ACC
}

// ---------------------------------------------------------------- fused SpMM+GEMM
// Phase 1: OUT[r] = X[r] + sum_e vals[e]*dequant(XT8[cols[e]]); lane (l15,lg)
//   owns dst-row l15's cols {s*32+lg*8..+8} -> accumulators ARE the MFMA
//   B-fragments (no LDS, no sync).
// Phase 2: xt8_next = quant(OUT @ Wt) via 32 MFMA/wave, R4 epilogue.
__global__ __launch_bounds__(256) void spmm_fused_kernel(
    const unsigned char* __restrict__ XT8, const float* __restrict__ scale_in,
    const float* __restrict__ X, const int* __restrict__ row_ptr,
    const int* __restrict__ cols, const float* __restrict__ vals,
    const ushort* __restrict__ Wt, float* __restrict__ OUT,
    unsigned char* __restrict__ Y8, float* __restrict__ scale_out) {
  const int tid  = threadIdx.x;
  const int wave = tid >> 6;
  const int lane = tid & 63;
  const int l15  = lane & 15;
  const int lg   = lane >> 4;
  const int row  = blockIdx.x * 64 + wave * 16 + l15;
  const int rowc = row < N_USERS ? row : N_USERS - 1;
  const bool act = row < N_USERS;
  const int start = row_ptr[rowc];
  const int end   = row_ptr[rowc + 1];

  float acc[4][8];
  #pragma unroll
  for (int s = 0; s < 4; ++s)
    #pragma unroll
    for (int j = 0; j < 8; ++j) acc[s][j] = 0.f;
  float vsum = 0.f;

  const uint2* base2 = (const uint2*)XT8;   // row = 16 uint2; idx s*4+lg
  int e = start;
  int e_pre = (start + 3) & ~3;
  if (e_pre > end) e_pre = end;
  for (; e < e_pre; ++e) {
    int c = cols[e];
    float vs = vals[e] * scale_in[c];
    vsum += vs;
    const uint2* src = base2 + (size_t)c * 16 + lg;
    uint2 g0 = src[0], g1 = src[4], g2 = src[8], g3 = src[12];
    fma8b(acc[0], g0, vs); fma8b(acc[1], g1, vs);
    fma8b(acc[2], g2, vs); fma8b(acc[3], g3, vs);
  }
  for (; e + 4 <= end; e += 4) {
    int4   ca = *(const int4*)(cols + e);
    float4 va = *(const float4*)(vals + e);
    float vs0 = va.x * scale_in[ca.x], vs1 = va.y * scale_in[ca.y];
    float vs2 = va.z * scale_in[ca.z], vs3 = va.w * scale_in[ca.w];
    vsum += vs0 + vs1 + vs2 + vs3;
    const uint2* s0 = base2 + (size_t)ca.x * 16 + lg;
    const uint2* s1 = base2 + (size_t)ca.y * 16 + lg;
    const uint2* s2 = base2 + (size_t)ca.z * 16 + lg;
    const uint2* s3 = base2 + (size_t)ca.w * 16 + lg;
    uint2 a0 = s0[0], a1 = s0[4], a2 = s0[8],  a3 = s0[12];
    uint2 b0 = s1[0], b1 = s1[4], b2 = s1[8],  b3 = s1[12];
    uint2 c0 = s2[0], c1 = s2[4], c2 = s2[8],  c3 = s2[12];
    uint2 d0 = s3[0], d1 = s3[4], d2 = s3[8],  d3 = s3[12];
    fma8b(acc[0], a0, vs0); fma8b(acc[1], a1, vs0);
    fma8b(acc[2], a2, vs0); fma8b(acc[3], a3, vs0);
    fma8b(acc[0], b0, vs1); fma8b(acc[1], b1, vs1);
    fma8b(acc[2], b2, vs1); fma8b(acc[3], b3, vs1);
    fma8b(acc[0], c0, vs2); fma8b(acc[1], c1, vs2);
    fma8b(acc[2], c2, vs2); fma8b(acc[3], c3, vs2);
    fma8b(acc[0], d0, vs3); fma8b(acc[1], d1, vs3);
    fma8b(acc[2], d2, vs3); fma8b(acc[3], d3, vs3);
  }
  for (; e < end; ++e) {
    int c = cols[e];
    float vs = vals[e] * scale_in[c];
    vsum += vs;
    const uint2* src = base2 + (size_t)c * 16 + lg;
    uint2 g0 = src[0], g1 = src[4], g2 = src[8], g3 = src[12];
    fma8b(acc[0], g0, vs); fma8b(acc[1], g1, vs);
    fma8b(acc[2], g2, vs); fma8b(acc[3], g3, vs);
  }

  // residual + OUT write + bf16 b-frag pack (in-register)
  const float corr = vsum * 128.0f;
  union { bf16x8 v; uint4 u; } bfr[4];
  #pragma unroll
  for (int s = 0; s < 4; ++s) {
    const float* xr = X + (size_t)rowc * EMBED + s * 32 + lg * 8;
    float4 ra = *(const float4*)xr;
    float4 rb = *(const float4*)(xr + 4);
    float o0 = acc[s][0] - corr + ra.x, o1 = acc[s][1] - corr + ra.y;
    float o2 = acc[s][2] - corr + ra.z, o3 = acc[s][3] - corr + ra.w;
    float o4 = acc[s][4] - corr + rb.x, o5 = acc[s][5] - corr + rb.y;
    float o6 = acc[s][6] - corr + rb.z, o7 = acc[s][7] - corr + rb.w;
    if (act) {
      float* orow = OUT + (size_t)row * EMBED + s * 32 + lg * 8;
      *(float4*)orow       = (float4){o0, o1, o2, o3};
      *(float4*)(orow + 4) = (float4){o4, o5, o6, o7};
    }
    asm("v_cvt_pk_bf16_f32 %0, %1, %2" : "=v"(bfr[s].u.x) : "v"(o0), "v"(o1));
    asm("v_cvt_pk_bf16_f32 %0, %1, %2" : "=v"(bfr[s].u.y) : "v"(o2), "v"(o3));
    asm("v_cvt_pk_bf16_f32 %0, %1, %2" : "=v"(bfr[s].u.z) : "v"(o4), "v"(o5));
    asm("v_cvt_pk_bf16_f32 %0, %1, %2" : "=v"(bfr[s].u.w) : "v"(o6), "v"(o7));
  }

  // fused GEMM: accg[nt] covers output cols nt*16 + lg*4 + i of user row l15
  f32x4 accg[8];
  #pragma unroll
  for (int t = 0; t < 8; ++t) accg[t] = (f32x4){0.f, 0.f, 0.f, 0.f};
  #pragma unroll
  for (int s = 0; s < 4; ++s) {
    const int k0 = s * 32 + lg * 8;
    #pragma unroll
    for (int nt = 0; nt < 8; ++nt) {
      union { bf16x8 v; uint4 u; } afr;
      afr.u = *(const uint4*)(Wt + (size_t)(nt * 16 + l15) * 128 + k0);
      accg[nt] = __builtin_amdgcn_mfma_f32_16x16x32_bf16(afr.v, bfr[s].v, accg[nt], 0, 0, 0);
    }
  }

  if (act) {
    float amax = 0.f;
    #pragma unroll
    for (int nt = 0; nt < 8; ++nt)
      #pragma unroll
      for (int i = 0; i < 4; ++i) amax = fmaxf(amax, fabsf(accg[nt][i]));
    amax = fmaxf(amax, __shfl_xor(amax, 16));
    amax = fmaxf(amax, __shfl_xor(amax, 32));
    const float inv = amax > 0.f ? 127.0f / amax : 0.f;
    if (lg == 0) scale_out[row] = amax * (1.0f / 127.0f);

    unsigned char* yrow = Y8 + (size_t)row * EMBED;
    #pragma unroll
    for (int nt = 0; nt < 8; ++nt) {
      uint q = 0;
      #pragma unroll
      for (int i = 0; i < 4; ++i) {
        int qi = __float2int_rn(accg[nt][i] * inv) + 128;
        q |= (uint)qi << (8 * i);
      }
      *(uint*)(yrow + nt * 16 + lg * 4) = q;
    }
  }
}

// ---------------------------------------------------------------- plain SpMM (final layer)
__device__ __forceinline__ void fma16(float* acc, uint4 g, float vs) {
  float f;
  #define CVT_ACC(word, b, slot)                                        \
    asm("v_cvt_f32_ubyte" #b " %0, %1" : "=v"(f) : "v"(word));          \
    acc[slot] = fmaf(vs, f, acc[slot]);
  CVT_ACC(g.x, 0, 0)  CVT_ACC(g.x, 1, 1)  CVT_ACC(g.x, 2, 2)  CVT_ACC(g.x, 3, 3)
  CVT_ACC(g.y, 0, 4)  CVT_ACC(g.y, 1, 5)  CVT_ACC(g.y, 2, 6)  CVT_ACC(g.y, 3, 7)
  CVT_ACC(g.z, 0, 8)  CVT_ACC(g.z, 1, 9)  CVT_ACC(g.z, 2, 10) CVT_ACC(g.z, 3, 11)
  CVT_ACC(g.w, 0, 12) CVT_ACC(g.w, 1, 13) CVT_ACC(g.w, 2, 14) CVT_ACC(g.w, 3, 15)
  #undef CVT_ACC
}

__global__ __launch_bounds__(256) void spmm_kernel(const unsigned char* __restrict__ XT8,
                                                   const float* __restrict__ scale_arr,
                                                   const float* __restrict__ X,
                                                   const int* __restrict__ row_ptr,
                                                   const int* __restrict__ cols,
                                                   const float* __restrict__ vals,
                                                   float* __restrict__ OUT) {
  const int tid = threadIdx.x;
  const int l   = tid & 7;
  const int rg  = tid >> 3;
  const int row = blockIdx.x * 32 + rg;
  if (row >= N_USERS) return;
  const int start = row_ptr[row];
  const int end   = row_ptr[row + 1];
  const uint4* XT4 = (const uint4*)XT8;

  float acc[16];
  #pragma unroll
  for (int j = 0; j < 16; ++j) acc[j] = 0.f;
  float vsum = 0.f;

  int e = start;
  int e_pre = (start + 3) & ~3;
  if (e_pre > end) e_pre = end;
  for (; e < e_pre; ++e) {
    int c = cols[e];
    float vs = vals[e] * scale_arr[c];
    vsum += vs;
    fma16(acc, XT4[(size_t)c * 8 + l], vs);
  }
  for (; e + 4 <= end; e += 4) {
    int4   ca = *(const int4*)(cols + e);
    float4 va = *(const float4*)(vals + e);
    float vs0 = va.x * scale_arr[ca.x], vs1 = va.y * scale_arr[ca.y];
    float vs2 = va.z * scale_arr[ca.z], vs3 = va.w * scale_arr[ca.w];
    uint4 g0 = XT4[(size_t)ca.x * 8 + l];
    uint4 g1 = XT4[(size_t)ca.y * 8 + l];
    uint4 g2 = XT4[(size_t)ca.z * 8 + l];
    uint4 g3 = XT4[(size_t)ca.w * 8 + l];
    vsum += vs0 + vs1 + vs2 + vs3;
    fma16(acc, g0, vs0);
    fma16(acc, g1, vs1);
    fma16(acc, g2, vs2);
    fma16(acc, g3, vs3);
  }
  for (; e < end; ++e) {
    int c = cols[e];
    float vs = vals[e] * scale_arr[c];
    vsum += vs;
    fma16(acc, XT4[(size_t)c * 8 + l], vs);
  }

  const float corr = vsum * 128.0f;
  const float* xr = X + (size_t)row * EMBED + l * 16;
  float*       orow = OUT + (size_t)row * EMBED + l * 16;
  #pragma unroll
  for (int k = 0; k < 4; ++k) {
    float4 r = *(const float4*)(xr + k * 4);
    float4 o = {acc[k * 4 + 0] - corr + r.x,
                acc[k * 4 + 1] - corr + r.y,
                acc[k * 4 + 2] - corr + r.z,
                acc[k * 4 + 3] - corr + r.w};
    *(float4*)(orow + k * 4) = o;
  }
}

// ---------------------------------------------------------------- launch
extern "C" void kernel_launch(void* const* d_in, const int* in_sizes, int n_in,
                              void* d_out, int out_size, void* d_ws, size_t ws_size,
                              hipStream_t stream) {
  const float* user_embeds = (const float*)d_in[0];
  const int*   s_rows      = (const int*)d_in[1];
  const int*   s_cols      = (const int*)d_in[2];
  const float* s_values    = (const float*)d_in[3];
  const float* W0          = (const float*)d_in[4];
  const float* W1          = (const float*)d_in[5];
  float* out = (float*)d_out;

  const int n_edges = in_sizes[1];
  const size_t layer = (size_t)N_USERS * EMBED;

  char* ws = (char*)d_ws;
  unsigned char* xt8a = (unsigned char*)ws;  ws += layer;                    // 12.8 MB
  unsigned char* xt8b = (unsigned char*)ws;  ws += layer;                    // 12.8 MB
  float*  scale_a = (float*)ws;              ws += N_USERS * sizeof(float);
  float*  scale_b = (float*)ws;              ws += N_USERS * sizeof(float);
  ushort* Wt0     = (ushort*)ws;             ws += 128 * 128 * sizeof(ushort);
  ushort* Wt1     = (ushort*)ws;             ws += 128 * 128 * sizeof(ushort);
  int*    row_ptr = (int*)ws;

  rowptr_kernel<<<(N_USERS + 1 + 255) / 256, 256, 0, stream>>>(
      s_rows, row_ptr, N_USERS, n_edges);
  wconv_kernel<<<2, 256, 0, stream>>>(W0, W1, (uint*)Wt0, (uint*)Wt1);

  // layer 0 GEMM: user_embeds @ W0 -> xt8a; also copies user_embeds -> out[0]
  gemm_kernel<<<(N_USERS + 63) / 64, 256, 0, stream>>>(
      user_embeds, Wt0, xt8a, scale_a, out);
  // fused: out[1] = user_embeds + S*deq(xt8a); xt8b = quant(out[1] @ W1)
  spmm_fused_kernel<<<(N_USERS + 63) / 64, 256, 0, stream>>>(
      xt8a, scale_a, user_embeds, row_ptr, s_cols, s_values, Wt1,
      out + layer, xt8b, scale_b);
  // final: out[2] = out[1] + S*deq(xt8b)
  spmm_kernel<<<(N_USERS + 31) / 32, 256, 0, stream>>>(
      xt8b, scale_b, out + layer, row_ptr, s_cols, s_values, out + 2 * layer);
}

// Round 13
// 202.577 us; speedup vs baseline: 1.1183x; 1.1183x over previous
//
#include <hip/hip_runtime.h>

#define N_USERS  100000
#define EMBED    128

typedef __attribute__((ext_vector_type(8))) short bf16x8;
typedef __attribute__((ext_vector_type(4))) float f32x4;

// xt8 rows are stored FRAGMENT-MAJOR: logical col c = s*32 + L*8 + j
// (s=0..3, L=0..3, j=0..7) lives at byte L*32 + s*8 + j. Lane L of the
// fused spmm then reads its 4 MFMA b-fragments as 2 contiguous uint4.

// ---------------------------------------------------------------- row pointers
__global__ __launch_bounds__(256) void rowptr_kernel(const int* __restrict__ rows,
                                                     int* __restrict__ row_ptr,
                                                     int n_rows, int n_edges) {
  int r = blockIdx.x * blockDim.x + threadIdx.x;
  if (r > n_rows) return;
  int lo = 0, hi = n_edges;
  while (lo < hi) {
    int mid = (lo + hi) >> 1;
    if (rows[mid] < r) lo = mid + 1; else hi = mid;
  }
  row_ptr[r] = lo;
}

// ---------------------------------------------------------------- W -> Wt bf16
__global__ __launch_bounds__(256) void wconv_kernel(const float* __restrict__ W0,
                                                    const float* __restrict__ W1,
                                                    uint* __restrict__ Wt0,
                                                    uint* __restrict__ Wt1) {
  const float* W  = blockIdx.x ? W1 : W0;
  uint*        Wt = blockIdx.x ? Wt1 : Wt0;
  for (int idx = threadIdx.x; idx < 128 * 64; idx += 256) {
    int n = idx >> 6;
    int kp = idx & 63;
    float a = W[(2 * kp) * 128 + n];
    float b = W[(2 * kp + 1) * 128 + n];
    uint o;
    asm("v_cvt_pk_bf16_f32 %0, %1, %2" : "=v"(o) : "v"(a), "v"(b));
    Wt[n * 64 + kp] = o;
  }
}

// ---------------------------------------------------------------- MFMA GEMM
// Y8 = quant(X @ W) per-row scale, FRAGMENT-MAJOR store. Streams X -> Xcopy.
__global__ __launch_bounds__(256) void gemm_kernel(const float* __restrict__ X,
                                                   const ushort* __restrict__ Wt,
                                                   unsigned char* __restrict__ Y8,
                                                   float* __restrict__ scale_arr,
                                                   float* __restrict__ Xcopy) {
  const int tid  = threadIdx.x;
  const int wave = tid >> 6;
  const int lane = tid & 63;
  const int l15  = lane & 15;
  const int lg   = lane >> 4;
  const int m    = blockIdx.x * 64 + wave * 16 + l15;
  const int mc   = m < N_USERS ? m : N_USERS - 1;
  const bool act = m < N_USERS;
  const float* xrow = X + (size_t)mc * EMBED;

  f32x4 acc[8];
  #pragma unroll
  for (int t = 0; t < 8; ++t) acc[t] = (f32x4){0.f, 0.f, 0.f, 0.f};

  #pragma unroll
  for (int s = 0; s < 4; ++s) {
    const int k0 = s * 32 + lg * 8;
    float4 xa = *(const float4*)(xrow + k0);
    float4 xb = *(const float4*)(xrow + k0 + 4);
    if (Xcopy && act) {
      *(float4*)(Xcopy + (size_t)m * EMBED + k0)     = xa;
      *(float4*)(Xcopy + (size_t)m * EMBED + k0 + 4) = xb;
    }
    union { bf16x8 v; uint u[4]; } bfr;
    asm("v_cvt_pk_bf16_f32 %0, %1, %2" : "=v"(bfr.u[0]) : "v"(xa.x), "v"(xa.y));
    asm("v_cvt_pk_bf16_f32 %0, %1, %2" : "=v"(bfr.u[1]) : "v"(xa.z), "v"(xa.w));
    asm("v_cvt_pk_bf16_f32 %0, %1, %2" : "=v"(bfr.u[2]) : "v"(xb.x), "v"(xb.y));
    asm("v_cvt_pk_bf16_f32 %0, %1, %2" : "=v"(bfr.u[3]) : "v"(xb.z), "v"(xb.w));
    #pragma unroll
    for (int nt = 0; nt < 8; ++nt) {
      union { bf16x8 v; uint4 u; } afr;
      afr.u = *(const uint4*)(Wt + (size_t)(nt * 16 + l15) * 128 + k0);
      acc[nt] = __builtin_amdgcn_mfma_f32_16x16x32_bf16(afr.v, bfr.v, acc[nt], 0, 0, 0);
    }
  }

  if (act) {
    float amax = 0.f;
    #pragma unroll
    for (int nt = 0; nt < 8; ++nt)
      #pragma unroll
      for (int i = 0; i < 4; ++i) amax = fmaxf(amax, fabsf(acc[nt][i]));
    amax = fmaxf(amax, __shfl_xor(amax, 16));
    amax = fmaxf(amax, __shfl_xor(amax, 32));
    const float inv = amax > 0.f ? 127.0f / amax : 0.f;
    if (lg == 0) scale_arr[m] = amax * (1.0f / 127.0f);

    uint* yrow = (uint*)(Y8 + (size_t)m * EMBED);
    #pragma unroll
    for (int nt = 0; nt < 8; ++nt) {
      uint q = 0;
      #pragma unroll
      for (int i = 0; i < 4; ++i) {
        int qi = __float2int_rn(acc[nt][i] * inv) + 128;   // 1..255
        q |= (uint)qi << (8 * i);
      }
      // fragment-major: u32 idx = hi2*8 + (nt>>1)*2 + (lg&1)
      yrow[(((nt & 1) << 1) | (lg >> 1)) * 8 + (nt >> 1) * 2 + (lg & 1)] = q;
    }
  }
}

// ---------------------------------------------------------------- dequant FMA
__device__ __forceinline__ void fma8b(float* a, uint w0, uint w1, float vs) {
  float f;
  #define CVT_ACC(word, b, slot)                                        \
    asm("v_cvt_f32_ubyte" #b " %0, %1" : "=v"(f) : "v"(word));          \
    a[slot] = fmaf(vs, f, a[slot]);
  CVT_ACC(w0, 0, 0) CVT_ACC(w0, 1, 1) CVT_ACC(w0, 2, 2) CVT_ACC(w0, 3, 3)
  CVT_ACC(w1, 0, 4) CVT_ACC(w1, 1, 5) CVT_ACC(w1, 2, 6) CVT_ACC(w1, 3, 7)
  #undef CVT_ACC
}

// ---------------------------------------------------------------- fused SpMM+GEMM
__global__ __launch_bounds__(256, 4) void spmm_fused_kernel(
    const unsigned char* __restrict__ XT8, const float* __restrict__ scale_in,
    const float* __restrict__ X, const int* __restrict__ row_ptr,
    const int* __restrict__ cols, const float* __restrict__ vals,
    const ushort* __restrict__ Wt, float* __restrict__ OUT,
    unsigned char* __restrict__ Y8, float* __restrict__ scale_out) {
  const int tid  = threadIdx.x;
  const int wave = tid >> 6;
  const int lane = tid & 63;
  const int l15  = lane & 15;
  const int lg   = lane >> 4;
  const int row  = blockIdx.x * 64 + wave * 16 + l15;
  const int rowc = row < N_USERS ? row : N_USERS - 1;
  const bool act = row < N_USERS;
  const int start = row_ptr[rowc];
  const int end   = row_ptr[rowc + 1];

  union AccU { float f[4][8]; f32x4 v[8]; } U;   // phase1 acc / phase2 accg
  #pragma unroll
  for (int t = 0; t < 8; ++t) U.v[t] = (f32x4){0.f, 0.f, 0.f, 0.f};
  float vsum = 0.f;

  const uint4* B8 = (const uint4*)XT8;   // row = 8 uint4; lane lg: idx lg*2, +1
  int e = start;
  int e_pre = (start + 3) & ~3;
  if (e_pre > end) e_pre = end;
  for (; e < e_pre; ++e) {
    int c = cols[e];
    float vs = vals[e] * scale_in[c];
    vsum += vs;
    uint4 ga = B8[(size_t)c * 8 + lg * 2];
    uint4 gb = B8[(size_t)c * 8 + lg * 2 + 1];
    fma8b(U.f[0], ga.x, ga.y, vs); fma8b(U.f[1], ga.z, ga.w, vs);
    fma8b(U.f[2], gb.x, gb.y, vs); fma8b(U.f[3], gb.z, gb.w, vs);
  }
  for (; e + 4 <= end; e += 4) {
    int4   ca = *(const int4*)(cols + e);
    float4 va = *(const float4*)(vals + e);
    float vs0 = va.x * scale_in[ca.x], vs1 = va.y * scale_in[ca.y];
    float vs2 = va.z * scale_in[ca.z], vs3 = va.w * scale_in[ca.w];
    vsum += vs0 + vs1 + vs2 + vs3;
    uint4 a0 = B8[(size_t)ca.x * 8 + lg * 2], a1 = B8[(size_t)ca.x * 8 + lg * 2 + 1];
    uint4 b0 = B8[(size_t)ca.y * 8 + lg * 2], b1 = B8[(size_t)ca.y * 8 + lg * 2 + 1];
    uint4 c0 = B8[(size_t)ca.z * 8 + lg * 2], c1 = B8[(size_t)ca.z * 8 + lg * 2 + 1];
    uint4 d0 = B8[(size_t)ca.w * 8 + lg * 2], d1 = B8[(size_t)ca.w * 8 + lg * 2 + 1];
    fma8b(U.f[0], a0.x, a0.y, vs0); fma8b(U.f[1], a0.z, a0.w, vs0);
    fma8b(U.f[2], a1.x, a1.y, vs0); fma8b(U.f[3], a1.z, a1.w, vs0);
    fma8b(U.f[0], b0.x, b0.y, vs1); fma8b(U.f[1], b0.z, b0.w, vs1);
    fma8b(U.f[2], b1.x, b1.y, vs1); fma8b(U.f[3], b1.z, b1.w, vs1);
    fma8b(U.f[0], c0.x, c0.y, vs2); fma8b(U.f[1], c0.z, c0.w, vs2);
    fma8b(U.f[2], c1.x, c1.y, vs2); fma8b(U.f[3], c1.z, c1.w, vs2);
    fma8b(U.f[0], d0.x, d0.y, vs3); fma8b(U.f[1], d0.z, d0.w, vs3);
    fma8b(U.f[2], d1.x, d1.y, vs3); fma8b(U.f[3], d1.z, d1.w, vs3);
  }
  for (; e < end; ++e) {
    int c = cols[e];
    float vs = vals[e] * scale_in[c];
    vsum += vs;
    uint4 ga = B8[(size_t)c * 8 + lg * 2];
    uint4 gb = B8[(size_t)c * 8 + lg * 2 + 1];
    fma8b(U.f[0], ga.x, ga.y, vs); fma8b(U.f[1], ga.z, ga.w, vs);
    fma8b(U.f[2], gb.x, gb.y, vs); fma8b(U.f[3], gb.z, gb.w, vs);
  }

  // residual + OUT write + bf16 b-frag pack; then U is reused for phase 2
  const float corr = vsum * 128.0f;
  union { bf16x8 v; uint4 u; } bfr[4];
  #pragma unroll
  for (int s = 0; s < 4; ++s) {
    const float* xr = X + (size_t)rowc * EMBED + s * 32 + lg * 8;
    float4 ra = *(const float4*)xr;
    float4 rb = *(const float4*)(xr + 4);
    float o0 = U.f[s][0] - corr + ra.x, o1 = U.f[s][1] - corr + ra.y;
    float o2 = U.f[s][2] - corr + ra.z, o3 = U.f[s][3] - corr + ra.w;
    float o4 = U.f[s][4] - corr + rb.x, o5 = U.f[s][5] - corr + rb.y;
    float o6 = U.f[s][6] - corr + rb.z, o7 = U.f[s][7] - corr + rb.w;
    if (act) {
      float* orow = OUT + (size_t)row * EMBED + s * 32 + lg * 8;
      *(float4*)orow       = (float4){o0, o1, o2, o3};
      *(float4*)(orow + 4) = (float4){o4, o5, o6, o7};
    }
    asm("v_cvt_pk_bf16_f32 %0, %1, %2" : "=v"(bfr[s].u.x) : "v"(o0), "v"(o1));
    asm("v_cvt_pk_bf16_f32 %0, %1, %2" : "=v"(bfr[s].u.y) : "v"(o2), "v"(o3));
    asm("v_cvt_pk_bf16_f32 %0, %1, %2" : "=v"(bfr[s].u.z) : "v"(o4), "v"(o5));
    asm("v_cvt_pk_bf16_f32 %0, %1, %2" : "=v"(bfr[s].u.w) : "v"(o6), "v"(o7));
  }

  // phase 2: accumulators reuse U.v (phase-1 values dead)
  #pragma unroll
  for (int t = 0; t < 8; ++t) U.v[t] = (f32x4){0.f, 0.f, 0.f, 0.f};
  #pragma unroll
  for (int s = 0; s < 4; ++s) {
    const int k0 = s * 32 + lg * 8;
    #pragma unroll
    for (int nt = 0; nt < 8; ++nt) {
      union { bf16x8 v; uint4 u; } afr;
      afr.u = *(const uint4*)(Wt + (size_t)(nt * 16 + l15) * 128 + k0);
      U.v[nt] = __builtin_amdgcn_mfma_f32_16x16x32_bf16(afr.v, bfr[s].v, U.v[nt], 0, 0, 0);
    }
  }

  if (act) {
    float amax = 0.f;
    #pragma unroll
    for (int nt = 0; nt < 8; ++nt)
      #pragma unroll
      for (int i = 0; i < 4; ++i) amax = fmaxf(amax, fabsf(U.v[nt][i]));
    amax = fmaxf(amax, __shfl_xor(amax, 16));
    amax = fmaxf(amax, __shfl_xor(amax, 32));
    const float inv = amax > 0.f ? 127.0f / amax : 0.f;
    if (lg == 0) scale_out[row] = amax * (1.0f / 127.0f);

    uint* yrow = (uint*)(Y8 + (size_t)row * EMBED);
    #pragma unroll
    for (int nt = 0; nt < 8; ++nt) {
      uint q = 0;
      #pragma unroll
      for (int i = 0; i < 4; ++i) {
        int qi = __float2int_rn(U.v[nt][i] * inv) + 128;
        q |= (uint)qi << (8 * i);
      }
      yrow[(((nt & 1) << 1) | (lg >> 1)) * 8 + (nt >> 1) * 2 + (lg & 1)] = q;
    }
  }
}

// ---------------------------------------------------------------- plain SpMM (final)
// Reads fragment-major rows; un-permutes at the f32 epilogue.
__device__ __forceinline__ void fma16(float* acc, uint4 g, float vs) {
  float f;
  #define CVT_ACC(word, b, slot)                                        \
    asm("v_cvt_f32_ubyte" #b " %0, %1" : "=v"(f) : "v"(word));          \
    acc[slot] = fmaf(vs, f, acc[slot]);
  CVT_ACC(g.x, 0, 0)  CVT_ACC(g.x, 1, 1)  CVT_ACC(g.x, 2, 2)  CVT_ACC(g.x, 3, 3)
  CVT_ACC(g.y, 0, 4)  CVT_ACC(g.y, 1, 5)  CVT_ACC(g.y, 2, 6)  CVT_ACC(g.y, 3, 7)
  CVT_ACC(g.z, 0, 8)  CVT_ACC(g.z, 1, 9)  CVT_ACC(g.z, 2, 10) CVT_ACC(g.z, 3, 11)
  CVT_ACC(g.w, 0, 12) CVT_ACC(g.w, 1, 13) CVT_ACC(g.w, 2, 14) CVT_ACC(g.w, 3, 15)
  #undef CVT_ACC
}

__global__ __launch_bounds__(256) void spmm_kernel(const unsigned char* __restrict__ XT8,
                                                   const float* __restrict__ scale_arr,
                                                   const float* __restrict__ X,
                                                   const int* __restrict__ row_ptr,
                                                   const int* __restrict__ cols,
                                                   const float* __restrict__ vals,
                                                   float* __restrict__ OUT) {
  const int tid = threadIdx.x;
  const int l   = tid & 7;
  const int rg  = tid >> 3;
  const int row = blockIdx.x * 32 + rg;
  if (row >= N_USERS) return;
  const int start = row_ptr[row];
  const int end   = row_ptr[row + 1];
  const uint4* XT4 = (const uint4*)XT8;

  float acc[16];
  #pragma unroll
  for (int j = 0; j < 16; ++j) acc[j] = 0.f;
  float vsum = 0.f;

  int e = start;
  int e_pre = (start + 3) & ~3;
  if (e_pre > end) e_pre = end;
  for (; e < e_pre; ++e) {
    int c = cols[e];
    float vs = vals[e] * scale_arr[c];
    vsum += vs;
    fma16(acc, XT4[(size_t)c * 8 + l], vs);
  }
  for (; e + 4 <= end; e += 4) {
    int4   ca = *(const int4*)(cols + e);
    float4 va = *(const float4*)(vals + e);
    float vs0 = va.x * scale_arr[ca.x], vs1 = va.y * scale_arr[ca.y];
    float vs2 = va.z * scale_arr[ca.z], vs3 = va.w * scale_arr[ca.w];
    uint4 g0 = XT4[(size_t)ca.x * 8 + l];
    uint4 g1 = XT4[(size_t)ca.y * 8 + l];
    uint4 g2 = XT4[(size_t)ca.z * 8 + l];
    uint4 g3 = XT4[(size_t)ca.w * 8 + l];
    vsum += vs0 + vs1 + vs2 + vs3;
    fma16(acc, g0, vs0);
    fma16(acc, g1, vs1);
    fma16(acc, g2, vs2);
    fma16(acc, g3, vs3);
  }
  for (; e < end; ++e) {
    int c = cols[e];
    float vs = vals[e] * scale_arr[c];
    vsum += vs;
    fma16(acc, XT4[(size_t)c * 8 + l], vs);
  }

  // bytes l*16..: slots 0..7 -> cols colA..+7, slots 8..15 -> colA+32..+39
  const float corr = vsum * 128.0f;
  const int colA = (l & 1) * 64 + (l >> 1) * 8;
  const float* xrA = X + (size_t)row * EMBED + colA;
  float*       orA = OUT + (size_t)row * EMBED + colA;
  float4 rA0 = *(const float4*)xrA;
  float4 rA1 = *(const float4*)(xrA + 4);
  float4 rB0 = *(const float4*)(xrA + 32);
  float4 rB1 = *(const float4*)(xrA + 36);
  *(float4*)orA        = (float4){acc[0] - corr + rA0.x,  acc[1] - corr + rA0.y,
                                  acc[2] - corr + rA0.z,  acc[3] - corr + rA0.w};
  *(float4*)(orA + 4)  = (float4){acc[4] - corr + rA1.x,  acc[5] - corr + rA1.y,
                                  acc[6] - corr + rA1.z,  acc[7] - corr + rA1.w};
  *(float4*)(orA + 32) = (float4){acc[8] - corr + rB0.x,  acc[9] - corr + rB0.y,
                                  acc[10] - corr + rB0.z, acc[11] - corr + rB0.w};
  *(float4*)(orA + 36) = (float4){acc[12] - corr + rB1.x, acc[13] - corr + rB1.y,
                                  acc[14] - corr + rB1.z, acc[15] - corr + rB1.w};
}

// ---------------------------------------------------------------- launch
extern "C" void kernel_launch(void* const* d_in, const int* in_sizes, int n_in,
                              void* d_out, int out_size, void* d_ws, size_t ws_size,
                              hipStream_t stream) {
  const float* user_embeds = (const float*)d_in[0];
  const int*   s_rows      = (const int*)d_in[1];
  const int*   s_cols      = (const int*)d_in[2];
  const float* s_values    = (const float*)d_in[3];
  const float* W0          = (const float*)d_in[4];
  const float* W1          = (const float*)d_in[5];
  float* out = (float*)d_out;

  const int n_edges = in_sizes[1];
  const size_t layer = (size_t)N_USERS * EMBED;

  char* ws = (char*)d_ws;
  unsigned char* xt8a = (unsigned char*)ws;  ws += layer;                    // 12.8 MB
  unsigned char* xt8b = (unsigned char*)ws;  ws += layer;                    // 12.8 MB
  float*  scale_a = (float*)ws;              ws += N_USERS * sizeof(float);
  float*  scale_b = (float*)ws;              ws += N_USERS * sizeof(float);
  ushort* Wt0     = (ushort*)ws;             ws += 128 * 128 * sizeof(ushort);
  ushort* Wt1     = (ushort*)ws;             ws += 128 * 128 * sizeof(ushort);
  int*    row_ptr = (int*)ws;

  rowptr_kernel<<<(N_USERS + 1 + 255) / 256, 256, 0, stream>>>(
      s_rows, row_ptr, N_USERS, n_edges);
  wconv_kernel<<<2, 256, 0, stream>>>(W0, W1, (uint*)Wt0, (uint*)Wt1);

  // layer 0 GEMM: user_embeds @ W0 -> xt8a (frag-major); copies ue -> out[0]
  gemm_kernel<<<(N_USERS + 63) / 64, 256, 0, stream>>>(
      user_embeds, Wt0, xt8a, scale_a, out);
  // fused: out[1] = ue + S*deq(xt8a); xt8b = quant(out[1] @ W1) (frag-major)
  spmm_fused_kernel<<<(N_USERS + 63) / 64, 256, 0, stream>>>(
      xt8a, scale_a, user_embeds, row_ptr, s_cols, s_values, Wt1,
      out + layer, xt8b, scale_b);
  // final: out[2] = out[1] + S*deq(xt8b)
  spmm_kernel<<<(N_USERS + 31) / 32, 256, 0, stream>>>(
      xt8b, scale_b, out + layer, row_ptr, s_cols, s_values, out + 2 * layer);
}